// Round 2
// baseline (269.241 us; speedup 1.0000x reference)
//
#include <hip/hip_runtime.h>

#define NSEG   800
#define BATCH  256
#define NFREQ  51
#define NELEM  (BATCH*NFREQ)      // 13056
#define NSAMP  80000
#define NBLK   (2*NSEG)           // 1600 K1 blocks (1 segment each)
#define NJ     16                 // reduce split
#define GPJ    (NSEG/NJ)          // 50 blocks per slab

typedef __attribute__((ext_vector_type(8))) short          short8;    // 8 bf16 = 4 VGPR
typedef __attribute__((ext_vector_type(4))) float          float4v;   // MFMA acc

// ---------------- compile-time window + trig (double Taylor, exact to fp32) ----------------
constexpr double TCPI  = 3.14159265358979323846264338327950288;
constexpr double TC2PI = 6.28318530717958647692528676655900577;

constexpr double taylor_cos(double y) {   // |y| <= pi
    double y2 = y * y, term = 1.0, sum = 1.0;
    for (int j = 1; j <= 26; ++j) { term *= -y2 / (double)((2*j-1)*(2*j)); sum += term; }
    return sum;
}
constexpr double cos_k(int k) {           // cos(2*pi*(k%100)/100)
    return -taylor_cos(TC2PI * (double)(k % 100) / 100.0 - TCPI);
}
struct WinT { float w[100]; };
constexpr WinT make_win() {
    WinT t{};
    for (int k = 0; k < 100; ++k) t.w[k] = (float)(1.0 - cos_k(k));   // hann(periodic)*2
    return t;
}
__device__ const WinT d_wt = make_win();

struct TrigT { float c[100]; float s[100]; };
constexpr TrigT make_trig() {
    TrigT t{};
    for (int m = 0; m < 100; ++m) {
        t.c[m] = (float)cos_k(m);                 // cos(2*pi*m/100)
        t.s[m] = (float)cos_k((m + 75) % 100);    // sin(2*pi*m/100) = cos(2*pi*(m+75)/100)
    }
    return t;
}
__device__ const TrigT d_tt = make_trig();

// ---------------- bf16 helpers (RN-even) ----------------
__device__ __forceinline__ unsigned short f2bf(float x) {
    unsigned int u = __float_as_uint(x);
    return (unsigned short)((u + 0x7FFFu + ((u >> 16) & 1u)) >> 16);
}
__device__ __forceinline__ float bf2f(unsigned short h) {
    return __uint_as_float(((unsigned int)h) << 16);
}

// clamp+window+convert 8 consecutive samples -> bf16 A-fragment
__device__ __forceinline__ short8 conv8(float4 a, float4 b, float4 wa, float4 wb) {
    short8 r;
    r[0] = (short)f2bf(fmaxf(a.x, 1e-6f) * wa.x);
    r[1] = (short)f2bf(fmaxf(a.y, 1e-6f) * wa.y);
    r[2] = (short)f2bf(fmaxf(a.z, 1e-6f) * wa.z);
    r[3] = (short)f2bf(fmaxf(a.w, 1e-6f) * wa.w);
    r[4] = (short)f2bf(fmaxf(b.x, 1e-6f) * wb.x);
    r[5] = (short)f2bf(fmaxf(b.y, 1e-6f) * wb.y);
    r[6] = (short)f2bf(fmaxf(b.z, 1e-6f) * wb.z);
    r[7] = (short)f2bf(fmaxf(b.w, 1e-6f) * wb.w);
    return r;
}

// order-preserving float<->uint key (monotone; min/max commutative => deterministic)
__device__ __forceinline__ unsigned int f2key(float x) {
    unsigned int b = __float_as_uint(x);
    return (b & 0x80000000u) ? ~b : (b | 0x80000000u);
}
__device__ __forceinline__ float key2f(unsigned int k) {
    return __uint_as_float((k & 0x80000000u) ? (k ^ 0x80000000u) : ~k);
}

// ---------------- K0: twiddle tables in MFMA B-frag order ----------------
// tw[pt][lane][j], pt=(kt*4+nt)*4+typ, typ: 0=Chi 1=Clo 2=Shi 3=Slo
// B[k=quad*8+j][f=lane&15]; zero for f>=51 or k>=100
__global__ void gen_tw_kernel(unsigned short* __restrict__ tw)
{
    int tid  = blockIdx.x * 256 + threadIdx.x;   // < 4096
    int lane = tid & 63, pt = tid >> 6;          // pt < 64
    int typ = pt & 3, nt = (pt >> 2) & 3, kt = pt >> 4;
    int f    = nt * 16 + (lane & 15);
    #pragma unroll
    for (int j = 0; j < 8; ++j) {
        int n = kt * 32 + (lane >> 4) * 8 + j;
        unsigned short outv = 0;
        if (f < 51 && n < 100) {
            int m = (n * f) % 100;
            float c = (typ < 2) ? d_tt.c[m] : d_tt.s[m];
            unsigned short h = f2bf(c);
            outv = (typ & 1) ? f2bf(c - bf2f(h)) : h;
        }
        tw[(pt << 9) + (lane << 3) + j] = outv;
    }
}

// ---------------- K1: per-segment MFMA DFT straight from global ----------------
// No LDS staging: A-fragments are 8 consecutive floats of one row -> load float4 x2,
// clamp/window/convert in registers. Log-PSD held in 32 registers; per-group min/max
// via LDS atomic min/max on order-preserving keys (commutative => deterministic).
// LDS ~2.1 KB. Occupancy: VGPR-bound, 2 blocks/CU (4 waves/EU).
__global__ void __launch_bounds__(512) __attribute__((amdgpu_waves_per_eu(4)))
psd_seg_kernel(const float* __restrict__ fake, const float* __restrict__ real,
               float* __restrict__ part, float* __restrict__ saArr,
               const unsigned short* __restrict__ tw)
{
    __shared__ unsigned int mnU[256], mxU[256];
    __shared__ float red8[8];

    const int bx = blockIdx.x;
    const int a  = bx >= NSEG;
    const int s  = a ? bx - NSEG : bx;
    const int t  = threadIdx.x;
    const int lane = t & 63, wv = t >> 6;
    const int col = lane & 15, quad = lane >> 4;
    const float* __restrict__ src = a ? real : fake;

    if (t < 256) mnU[t] = 0xFFFFFFFFu;
    else         mxU[t - 256] = 0u;
    __syncthreads();

    // A rows for this lane: mt=0 -> 32*wv+col, mt=1 -> +16
    const float* __restrict__ rp0 = src + (size_t)(32 * wv + col) * NSAMP + (size_t)s * 100;
    const float* __restrict__ rp1 = rp0 + (size_t)16 * NSAMP;
    const float4* __restrict__ w4 = (const float4*)d_wt.w;

    float4v accRe[2][4] = {};
    float4v accIm[2][4] = {};

    #pragma unroll 1
    for (int kt = 0; kt < 4; ++kt) {
        short8 xa0, xa1;
        if (kt < 3) {
            const int k0 = kt * 32 + quad * 8;
            float4 a0 = *(const float4*)(rp0 + k0);
            float4 a1 = *(const float4*)(rp0 + k0 + 4);
            float4 b0 = *(const float4*)(rp1 + k0);
            float4 b1 = *(const float4*)(rp1 + k0 + 4);
            float4 w0 = w4[kt * 8 + quad * 2];
            float4 w1 = w4[kt * 8 + quad * 2 + 1];
            xa0 = conv8(a0, a1, w0, w1);
            xa1 = conv8(b0, b1, w0, w1);
        } else {
            short8 z = {0, 0, 0, 0, 0, 0, 0, 0};
            xa0 = z; xa1 = z;
            if (quad == 0) {                       // k = 96..99 valid only
                float4 a0 = *(const float4*)(rp0 + 96);
                float4 b0 = *(const float4*)(rp1 + 96);
                float4 w0 = w4[24];
                xa0[0] = (short)f2bf(fmaxf(a0.x, 1e-6f) * w0.x);
                xa0[1] = (short)f2bf(fmaxf(a0.y, 1e-6f) * w0.y);
                xa0[2] = (short)f2bf(fmaxf(a0.z, 1e-6f) * w0.z);
                xa0[3] = (short)f2bf(fmaxf(a0.w, 1e-6f) * w0.w);
                xa1[0] = (short)f2bf(fmaxf(b0.x, 1e-6f) * w0.x);
                xa1[1] = (short)f2bf(fmaxf(b0.y, 1e-6f) * w0.y);
                xa1[2] = (short)f2bf(fmaxf(b0.z, 1e-6f) * w0.z);
                xa1[3] = (short)f2bf(fmaxf(b0.w, 1e-6f) * w0.w);
            }
        }
        const unsigned short* __restrict__ bkt = tw + (size_t)(kt * 16) * 512 + (lane << 3);
        #pragma unroll
        for (int nt = 0; nt < 4; ++nt) {
            const unsigned short* bp = bkt + (size_t)(nt * 4) * 512;
            short8 bCh = *(const short8*)(bp);
            short8 bCl = *(const short8*)(bp + 512);
            short8 bSh = *(const short8*)(bp + 1024);
            short8 bSl = *(const short8*)(bp + 1536);
            accRe[0][nt] = __builtin_amdgcn_mfma_f32_16x16x32_bf16(xa0, bCh, accRe[0][nt], 0, 0, 0);
            accRe[0][nt] = __builtin_amdgcn_mfma_f32_16x16x32_bf16(xa0, bCl, accRe[0][nt], 0, 0, 0);
            accIm[0][nt] = __builtin_amdgcn_mfma_f32_16x16x32_bf16(xa0, bSh, accIm[0][nt], 0, 0, 0);
            accIm[0][nt] = __builtin_amdgcn_mfma_f32_16x16x32_bf16(xa0, bSl, accIm[0][nt], 0, 0, 0);
            accRe[1][nt] = __builtin_amdgcn_mfma_f32_16x16x32_bf16(xa1, bCh, accRe[1][nt], 0, 0, 0);
            accRe[1][nt] = __builtin_amdgcn_mfma_f32_16x16x32_bf16(xa1, bCl, accRe[1][nt], 0, 0, 0);
            accIm[1][nt] = __builtin_amdgcn_mfma_f32_16x16x32_bf16(xa1, bSh, accIm[1][nt], 0, 0, 0);
            accIm[1][nt] = __builtin_amdgcn_mfma_f32_16x16x32_bf16(xa1, bSl, accIm[1][nt], 0, 0, 0);
        }
    }

    // ---- PSD -> signed clamp log -> registers (C/D: col=lane&15, row=quad*4+reg) ----
    float Lv[2][4][4];
    #pragma unroll
    for (int mt = 0; mt < 2; ++mt)
        #pragma unroll
        for (int nt = 0; nt < 4; ++nt)
            #pragma unroll
            for (int reg = 0; reg < 4; ++reg) {
                float re = accRe[mt][nt][reg], im = accIm[mt][nt][reg];
                float p  = fmaf(re, re, im * im);
                p        = fmaxf(p, 1e-38f);
                float lv = __logf(p);
                float al = fmaxf(fabsf(lv), 1e-6f);
                Lv[mt][nt][reg] = (lv > 0.0f) ? al : ((lv < 0.0f) ? -al : 0.0f);
            }

    // ---- group min/max via LDS atomics on monotone keys (group c = flat & 255) ----
    const bool v3 = (col < 3);                    // f<51 for nt==3
    #pragma unroll
    for (int mt = 0; mt < 2; ++mt)
        #pragma unroll
        for (int nt = 0; nt < 4; ++nt)
            if (nt < 3 || v3) {
                #pragma unroll
                for (int reg = 0; reg < 4; ++reg) {
                    int row  = 32 * wv + 16 * mt + quad * 4 + reg;
                    int flat = row * 51 + nt * 16 + col;
                    int c    = flat & 255;
                    unsigned int key = f2key(Lv[mt][nt][reg]);
                    atomicMin(&mnU[c], key);
                    atomicMax(&mxU[c], key);
                }
            }
    __syncthreads();
    if (t < 256) {
        float fmn = key2f(mnU[t]);
        float fmx = key2f(mxU[t]);
        mnU[t] = __float_as_uint(fmn);
        mxU[t] = __float_as_uint(1.0f / (fmx - fmn));
    }
    __syncthreads();

    // ---- normalize from registers + store + ssq ----
    float ssq = 0.0f;
    float* __restrict__ dst = part + (size_t)bx * NELEM;
    #pragma unroll
    for (int mt = 0; mt < 2; ++mt)
        #pragma unroll
        for (int nt = 0; nt < 4; ++nt)
            if (nt < 3 || v3) {
                #pragma unroll
                for (int reg = 0; reg < 4; ++reg) {
                    int row  = 32 * wv + 16 * mt + quad * 4 + reg;
                    int flat = row * 51 + nt * 16 + col;
                    int c    = flat & 255;
                    float mn  = __uint_as_float(mnU[c]);
                    float inv = __uint_as_float(mxU[c]);
                    float F = (Lv[mt][nt][reg] - mn) * inv;
                    ssq = fmaf(F, F, ssq);
                    dst[flat] = F;
                }
            }

    #pragma unroll
    for (int off = 32; off; off >>= 1) ssq += __shfl_down(ssq, off, 64);
    if (lane == 0) red8[wv] = ssq;
    __syncthreads();
    if (t == 0) {
        float acc = 0.0f;
        #pragma unroll
        for (int i = 0; i < 8; ++i) acc += red8[i];
        saArr[bx] = acc;
    }
}

// ---------------- K2a: partial column sums over 50-block slabs ----------------
__global__ void reduce_part_kernel(const float* __restrict__ part, float* __restrict__ pb)
{
    const int e = blockIdx.x * 256 + threadIdx.x;   // < 13056
    const int j = blockIdx.y;                        // < NJ
    const float* __restrict__ pF = part + (size_t)(j * GPJ) * NELEM + e;
    const float* __restrict__ pR = part + (size_t)(NSEG + j * GPJ) * NELEM + e;
    float sF = 0.0f, sR = 0.0f;
    #pragma unroll 5
    for (int i = 0; i < GPJ; ++i) {
        sF += pF[(size_t)i * NELEM];
        sR += pR[(size_t)i * NELEM];
    }
    pb[(size_t)(2 * j + 0) * NELEM + e] = sF;
    pb[(size_t)(2 * j + 1) * NELEM + e] = sR;
}

// ---------------- K2b: finish sums, per-e dot/ff, block reduce ----------------
__global__ void dot_kernel(const float* __restrict__ pb, double* __restrict__ k2out)
{
    __shared__ double red[2][4];
    const int t = threadIdx.x;
    const int e = blockIdx.x * 256 + t;
    float sF = 0.0f, sR = 0.0f;
    #pragma unroll
    for (int j = 0; j < NJ; ++j) {
        sF += pb[(size_t)(2 * j + 0) * NELEM + e];
        sR += pb[(size_t)(2 * j + 1) * NELEM + e];
    }
    double d  = (double)sF * (double)sR;
    double f2 = (double)sF * (double)sF;
    #pragma unroll
    for (int off = 32; off; off >>= 1) {
        d  += __shfl_down(d,  off, 64);
        f2 += __shfl_down(f2, off, 64);
    }
    if ((t & 63) == 0) { red[0][t >> 6] = d; red[1][t >> 6] = f2; }
    __syncthreads();
    if (t == 0) {
        k2out[2 * blockIdx.x + 0] = red[0][0] + red[0][1] + red[0][2] + red[0][3];
        k2out[2 * blockIdx.x + 1] = red[1][0] + red[1][1] + red[1][2] + red[1][3];
    }
}

// ---------------- K3: final combine in double ----------------
__global__ void final_kernel(const double* __restrict__ k2out, const float* __restrict__ saArr,
                             float* __restrict__ out)
{
    __shared__ double red[4][4];
    const int t = threadIdx.x;
    double d = 0.0, f2 = 0.0, sf = 0.0, sr = 0.0;
    if (t < NFREQ) { d = k2out[2 * t]; f2 = k2out[2 * t + 1]; }
    for (int i = t; i < NSEG; i += 256) {
        sf += (double)saArr[i];
        sr += (double)saArr[NSEG + i];
    }
    #pragma unroll
    for (int off = 32; off; off >>= 1) {
        d  += __shfl_down(d,  off, 64);
        f2 += __shfl_down(f2, off, 64);
        sf += __shfl_down(sf, off, 64);
        sr += __shfl_down(sr, off, 64);
    }
    const int w = t >> 6;
    if ((t & 63) == 0) { red[0][w] = d; red[1][w] = f2; red[2][w] = sf; red[3][w] = sr; }
    __syncthreads();
    if (t == 0) {
        double D  = red[0][0] + red[0][1] + red[0][2] + red[0][3];
        double FF = red[1][0] + red[1][1] + red[1][2] + red[1][3];
        double SF = red[2][0] + red[2][1] + red[2][2] + red[2][3];
        double SR = red[3][0] + red[3][1] + red[3][2] + red[3][3];

        const double n    = (double)NELEM;
        const double nseg = (double)NSEG;
        const double m    = nseg * (nseg - 1.0) * 0.5;

        out[0] = (float)((SF / nseg + SR / nseg - 2.0 * D / (nseg * nseg)) / n);
        out[1] = (float)((nseg * SF - FF) / (n * m));
    }
}

extern "C" void kernel_launch(void* const* d_in, const int* in_sizes, int n_in,
                              void* d_out, int out_size, void* d_ws, size_t ws_size,
                              hipStream_t stream) {
    const float* fake = (const float*)d_in[0];
    const float* real = (const float*)d_in[1];
    float* ws  = (float*)d_ws;
    float* out = (float*)d_out;

    // ws (floats): part[1600*13056] | saArr[1600] | pb[2*NJ*13056] | k2out (doubles) | tw (64KB)
    const size_t SA_FL = (size_t)NBLK * NELEM;            // 20,889,600
    const size_t PB_FL = SA_FL + NBLK;
    const size_t K2_BY = (PB_FL + (size_t)2 * NJ * NELEM) * 4;         // 8B-aligned
    const size_t TW_BY = (K2_BY + 2 * NFREQ * sizeof(double) + 63) & ~(size_t)63;

    float*          sa = ws + SA_FL;
    float*          pb = ws + PB_FL;
    double*         k2 = (double*)((char*)d_ws + K2_BY);
    unsigned short* tw = (unsigned short*)((char*)d_ws + TW_BY);

    gen_tw_kernel<<<16, 256, 0, stream>>>(tw);
    psd_seg_kernel<<<NBLK, 512, 0, stream>>>(fake, real, ws, sa, tw);
    reduce_part_kernel<<<dim3(NFREQ, NJ), 256, 0, stream>>>(ws, pb);
    dot_kernel<<<NFREQ, 256, 0, stream>>>(pb, k2);
    final_kernel<<<1, 256, 0, stream>>>(k2, sa, out);
}